// Round 2
// baseline (603.935 us; speedup 1.0000x reference)
//
#include <hip/hip_runtime.h>

#define NPTS 65536
#define QPB  2048   // queries per block
#define QPT  8      // queries per thread (256 threads * 8 = 2048)
#define CPB  4096   // target-chunk per block
#define ST   1024   // sub-tile staged in LDS (16 KB as float4)
#define NQBLK 32    // 65536 / 2048
#define NCBLK 16    // 65536 / 4096

// Each block: one direction, one query-block (2048 queries), one target chunk
// (4096 targets). Computes per-query min over the chunk of the true squared
// distance (|a|^2 added after the min-scan, then clamped >= 0) and
// atomicMin-combines (float bits as uint -- valid ONLY for non-negative
// floats, hence the clamp) into the global per-query min array.
__global__ __launch_bounds__(256) void chamfer_min_kernel(
    const float* __restrict__ A, const float* __restrict__ B,
    unsigned int* __restrict__ dmin)
{
    __shared__ float4 lds[ST];

    const int bid  = blockIdx.x;     // 0..1023
    const int dir  = bid >> 9;       // 0: A->B, 1: B->A
    const int r    = bid & 511;
    const int qblk = r >> 4;         // 0..31
    const int cblk = r & 15;         // 0..15

    const float* __restrict__ Q = dir ? B : A;
    const float* __restrict__ T = dir ? A : B;
    unsigned int* __restrict__ dm = dmin + dir * NPTS;

    const int t     = threadIdx.x;
    const int qbase = qblk * QPB;
    const int cbase = cblk * CPB;

    float qx[QPT], qy[QPT], qz[QPT], qsq[QPT], m[QPT];
#pragma unroll
    for (int k = 0; k < QPT; ++k) {
        const int q = qbase + k * 256 + t;
        const float x = Q[q * 3 + 0];
        const float y = Q[q * 3 + 1];
        const float z = Q[q * 3 + 2];
        qx[k] = x; qy[k] = y; qz[k] = z;
        qsq[k] = x * x + y * y + z * z;
        m[k]  = 3.4e38f;
    }

    for (int s = 0; s < CPB; s += ST) {
        __syncthreads();
        for (int p = t; p < ST; p += 256) {
            const int gp = cbase + s + p;
            const float x = T[gp * 3 + 0];
            const float y = T[gp * 3 + 1];
            const float z = T[gp * 3 + 2];
            lds[p] = make_float4(-2.0f * x, -2.0f * y, -2.0f * z,
                                 x * x + y * y + z * z);
        }
        __syncthreads();

#pragma unroll 4
        for (int j = 0; j < ST; ++j) {
            const float4 b = lds[j];   // broadcast read: all lanes same addr
#pragma unroll
            for (int k = 0; k < QPT; ++k) {
                // d' = |b|^2 - 2 a.b  (|a|^2 added after min; constant under min)
                const float d = fmaf(qx[k], b.x,
                                fmaf(qy[k], b.y,
                                fmaf(qz[k], b.z, b.w)));
                m[k] = fminf(m[k], d);
            }
        }
    }

#pragma unroll
    for (int k = 0; k < QPT; ++k) {
        // true squared distance, clamped >= 0 so uint-ordering == float-ordering
        const float v = fmaxf(m[k] + qsq[k], 0.0f);
        atomicMin(&dm[qbase + k * 256 + t], __float_as_uint(v));
    }
}

// Sum dmin over all 2*65536 queries; out += blockSum / 65536.
__global__ __launch_bounds__(256) void chamfer_reduce_kernel(
    const unsigned int* __restrict__ dmin,
    float* __restrict__ out)
{
    const int i = blockIdx.x * 256 + threadIdx.x;  // 0..131071 (grid = 512)
    float v = __uint_as_float(dmin[i]);

    // wave64 reduce
#pragma unroll
    for (int off = 32; off > 0; off >>= 1)
        v += __shfl_down(v, off, 64);

    __shared__ float ws[4];
    const int lane = threadIdx.x & 63;
    const int wid  = threadIdx.x >> 6;
    if (lane == 0) ws[wid] = v;
    __syncthreads();
    if (threadIdx.x == 0) {
        const float s = ws[0] + ws[1] + ws[2] + ws[3];
        atomicAdd(out, s * (1.0f / (float)NPTS));
    }
}

extern "C" void kernel_launch(void* const* d_in, const int* in_sizes, int n_in,
                              void* d_out, int out_size, void* d_ws, size_t ws_size,
                              hipStream_t stream)
{
    const float* A = (const float*)d_in[0];   // pc0 (65536,3) f32
    const float* B = (const float*)d_in[1];   // pc1 (65536,3) f32
    float* out = (float*)d_out;               // scalar f32
    unsigned int* dmin = (unsigned int*)d_ws; // 2*65536 u32 = 512 KB

    // init per-query mins to a huge positive float (0x7F7F7F7F ~ 3.39e38)
    hipMemsetAsync(dmin, 0x7F, 2 * NPTS * sizeof(unsigned int), stream);
    hipMemsetAsync(out, 0, sizeof(float), stream);

    chamfer_min_kernel<<<NQBLK * NCBLK * 2, 256, 0, stream>>>(A, B, dmin);
    chamfer_reduce_kernel<<<(2 * NPTS) / 256, 256, 0, stream>>>(dmin, out);
}

// Round 3
// 293.208 us; speedup vs baseline: 2.0598x; 2.0598x over previous
//
#include <hip/hip_runtime.h>

typedef __attribute__((ext_vector_type(8))) _Float16 f16x8;
typedef __attribute__((ext_vector_type(16))) float   f32x16;

#define NPTS   65536
#define ROWS   256      // rows (queries) per block
#define CH     1024     // target cols staged in LDS per chunk
#define JSLICE 8192     // target cols scanned per block
#define NSPLIT 8        // 65536 / JSLICE
#define NIBLK  256      // 65536 / ROWS

// K=16 packing of d(a,b) = |a|^2 + |b|^2 - 2 a.b into ONE f16 MFMA:
//  A row (query a):  h0:[ah0,ah1,ah2, al0,al1,al2, ah0,ah1] h1:[ah2, al0,al1,al2, 1,1,1, 0]
//  B col (target b): h0:[cx0,cx1,cx2, cx0,cx1,cx2, dx0,dx1] h1:[dx2, dx0,dx1,dx2, q0,q1,q2, 0]
//  where a = ah+al (f16 split), cx = -2*bh, dx = -2*bl, q0+q1+q2 = |b|^2 (3-term f16 split).
//  Inner product = -2(ah+al).(bh+bl) + |b|^2 ; |a|^2 added in f32 epilogue (const per row).
__global__ __launch_bounds__(512) void chamfer_mfma_kernel(
    const float* __restrict__ A, const float* __restrict__ B,
    unsigned int* __restrict__ dmin)
{
    __shared__ _Float16 Al[2 * ROWS * 8];   // 8 KB  [half][row][e]
    __shared__ float    Aq[ROWS];           // 1 KB  |a|^2 per row (f32)
    __shared__ _Float16 Bl[2 * CH * 8];     // 32 KB [half][col][e]

    const int bid  = blockIdx.x;
    const int dir  = bid >> 11;             // 0: A->B, 1: B->A
    const int r2   = bid & 2047;
    const int iblk = r2 >> 3;               // 0..255
    const int jsp  = r2 & 7;                // 0..7

    const float* __restrict__ Q = dir ? B : A;
    const float* __restrict__ T = dir ? A : B;
    unsigned int* __restrict__ dm = dmin + dir * NPTS;

    const int t     = threadIdx.x;
    const int lane  = t & 63;
    const int wid   = t >> 6;               // 0..7, wave owns rows [wid*32, +32)
    const int ibase = iblk * ROWS;
    const int jbase = jsp * JSLICE;

    // ---- pack A tile ----
    if (t < ROWS) {
        const float x = Q[(ibase + t) * 3 + 0];
        const float y = Q[(ibase + t) * 3 + 1];
        const float z = Q[(ibase + t) * 3 + 2];
        const _Float16 xh = (_Float16)x, yh = (_Float16)y, zh = (_Float16)z;
        const _Float16 xl = (_Float16)(x - (float)xh);
        const _Float16 yl = (_Float16)(y - (float)yh);
        const _Float16 zl = (_Float16)(z - (float)zh);
        const _Float16 one = (_Float16)1.0f, zero = (_Float16)0.0f;
        _Float16* p0 = &Al[t * 8];
        p0[0]=xh; p0[1]=yh; p0[2]=zh; p0[3]=xl; p0[4]=yl; p0[5]=zl; p0[6]=xh; p0[7]=yh;
        _Float16* p1 = &Al[ROWS * 8 + t * 8];
        p1[0]=zh; p1[1]=xl; p1[2]=yl; p1[3]=zl; p1[4]=one; p1[5]=one; p1[6]=one; p1[7]=zero;
        Aq[t] = fmaf(z, z, fmaf(y, y, x * x));
    }
    __syncthreads();

    // A fragment: lane -> row = lane&31 (within wave's 32-row band), k-half = lane>>5
    const f16x8 af = *(const f16x8*)&Al[(lane >> 5) * (ROWS * 8) + (wid * 32 + (lane & 31)) * 8];

    f32x16 zc;
#pragma unroll
    for (int i = 0; i < 16; ++i) zc[i] = 0.0f;

    float rmin[16];
#pragma unroll
    for (int i = 0; i < 16; ++i) rmin[i] = 3.4e38f;

    for (int ch = 0; ch < JSLICE / CH; ++ch) {
        __syncthreads();
        // ---- pack B chunk: CH cols, 512 threads -> 2 cols each ----
#pragma unroll
        for (int pp = 0; pp < 2; ++pp) {
            const int c = t + pp * 512;
            const int g = jbase + ch * CH + c;
            const float x = T[g * 3 + 0];
            const float y = T[g * 3 + 1];
            const float z = T[g * 3 + 2];
            const _Float16 xh = (_Float16)x, yh = (_Float16)y, zh = (_Float16)z;
            const _Float16 xl = (_Float16)(x - (float)xh);
            const _Float16 yl = (_Float16)(y - (float)yh);
            const _Float16 zl = (_Float16)(z - (float)zh);
            const _Float16 cx = (_Float16)(-2.0f * (float)xh);
            const _Float16 cy = (_Float16)(-2.0f * (float)yh);
            const _Float16 cz = (_Float16)(-2.0f * (float)zh);
            const _Float16 dx = (_Float16)(-2.0f * (float)xl);
            const _Float16 dy = (_Float16)(-2.0f * (float)yl);
            const _Float16 dz = (_Float16)(-2.0f * (float)zl);
            const float bq = fmaf(z, z, fmaf(y, y, x * x));
            const _Float16 q0 = (_Float16)bq;
            const float    r1 = bq - (float)q0;
            const _Float16 q1 = (_Float16)r1;
            const _Float16 q2 = (_Float16)(r1 - (float)q1);
            _Float16* p0 = &Bl[c * 8];
            p0[0]=cx; p0[1]=cy; p0[2]=cz; p0[3]=cx; p0[4]=cy; p0[5]=cz; p0[6]=dx; p0[7]=dy;
            _Float16* p1 = &Bl[CH * 8 + c * 8];
            p1[0]=dz; p1[1]=dx; p1[2]=dy; p1[3]=dz; p1[4]=q0; p1[5]=q1; p1[6]=q2; p1[7]=(_Float16)0.0f;
        }
        __syncthreads();

        // ---- 32 MFMAs over the chunk, processed in pairs for min3 fusion ----
#pragma unroll 4
        for (int jt = 0; jt < CH / 32; jt += 2) {
            const f16x8 bf0 = *(const f16x8*)&Bl[(lane >> 5) * (CH * 8) + (jt * 32 + (lane & 31)) * 8];
            const f16x8 bf1 = *(const f16x8*)&Bl[(lane >> 5) * (CH * 8) + ((jt + 1) * 32 + (lane & 31)) * 8];
            const f32x16 a0 = __builtin_amdgcn_mfma_f32_32x32x16_f16(af, bf0, zc, 0, 0, 0);
            const f32x16 a1 = __builtin_amdgcn_mfma_f32_32x32x16_f16(af, bf1, zc, 0, 0, 0);
#pragma unroll
            for (int r = 0; r < 16; ++r)
                rmin[r] = fminf(fminf(rmin[r], a0[r]), a1[r]);  // hopefully v_min3_f32
        }
    }

    // ---- finalize: min over the 32 col-residues (lane bits 0..4) ----
#pragma unroll
    for (int m = 1; m <= 16; m <<= 1) {
#pragma unroll
        for (int r = 0; r < 16; ++r)
            rmin[r] = fminf(rmin[r], __shfl_xor(rmin[r], m, 64));
    }
    // C layout: col = lane&31, row = (reg&3) + 8*(reg>>2) + 4*(lane>>5)
    if ((lane & 31) == 0) {
#pragma unroll
        for (int r = 0; r < 16; ++r) {
            const int rl = wid * 32 + (r & 3) + 8 * (r >> 2) + 4 * (lane >> 5);
            const float v = fmaxf(rmin[r] + Aq[rl], 0.0f);
            atomicMin(&dm[ibase + rl], __float_as_uint(v));
        }
    }
}

// Sum dmin over all 2*65536 queries; out += blockSum / 65536.
__global__ __launch_bounds__(256) void chamfer_reduce_kernel(
    const unsigned int* __restrict__ dmin,
    float* __restrict__ out)
{
    const int i = blockIdx.x * 256 + threadIdx.x;
    float v = __uint_as_float(dmin[i]);

#pragma unroll
    for (int off = 32; off > 0; off >>= 1)
        v += __shfl_down(v, off, 64);

    __shared__ float ws[4];
    const int lane = threadIdx.x & 63;
    const int wid  = threadIdx.x >> 6;
    if (lane == 0) ws[wid] = v;
    __syncthreads();
    if (threadIdx.x == 0) {
        const float s = ws[0] + ws[1] + ws[2] + ws[3];
        atomicAdd(out, s * (1.0f / (float)NPTS));
    }
}

extern "C" void kernel_launch(void* const* d_in, const int* in_sizes, int n_in,
                              void* d_out, int out_size, void* d_ws, size_t ws_size,
                              hipStream_t stream)
{
    const float* A = (const float*)d_in[0];   // pc0 (65536,3) f32
    const float* B = (const float*)d_in[1];   // pc1 (65536,3) f32
    float* out = (float*)d_out;               // scalar f32
    unsigned int* dmin = (unsigned int*)d_ws; // 2*65536 u32 = 512 KB

    hipMemsetAsync(dmin, 0x7F, 2 * NPTS * sizeof(unsigned int), stream);
    hipMemsetAsync(out, 0, sizeof(float), stream);

    chamfer_mfma_kernel<<<2 * NIBLK * NSPLIT, 512, 0, stream>>>(A, B, dmin);
    chamfer_reduce_kernel<<<(2 * NPTS) / 256, 256, 0, stream>>>(dmin, out);
}